// Round 5
// baseline (286.924 us; speedup 1.0000x reference)
//
#include <hip/hip_runtime.h>
#include <math.h>

// Problem constants
#define NT 3650
#define NG 2000
#define NYV 5
#define NCOL 10000      // NG*NYV flattened (g*5+v)
#define NYEARS 10
#define NDAY 365
#define TILE 16
#define NTILE 625       // NCOL/TILE
#define P 372           // padded LDS col stride in floats (rows 0..367 used)
#define STATS_N 6
#define STATS_FLOATS (2*NYEARS*NCOL*STATS_N)   // 1,200,000 floats
#define SE_BLOCKS (NYEARS*NTILE)               // 6250
#define K2_THREADS (NCOL*STATS_N)              // 60000
#define K2_BLOCKS ((K2_THREADS+255)/256)       // 235

// ---- cross-lane primitives (no per-call address VALU) ----

template<int IMM>
__device__ __forceinline__ float swzf(float v) {
  return __builtin_bit_cast(float, __builtin_amdgcn_ds_swizzle(__builtin_bit_cast(int, v), IMM));
}
template<int IMM>
__device__ __forceinline__ unsigned uswz(unsigned v) {
  return (unsigned)__builtin_amdgcn_ds_swizzle((int)v, IMM);
}
__device__ __forceinline__ float bpermf(int addr, float v) {
  return __builtin_bit_cast(float, __builtin_amdgcn_ds_bpermute(addr, __builtin_bit_cast(int, v)));
}
template<int CTRL>
__device__ __forceinline__ unsigned udpp(unsigned v) {
  return (unsigned)__builtin_amdgcn_update_dpp((int)v, (int)v, CTRL, 0xF, 0xF, true);
}

// full-wave float sum, result in all lanes; a32 = ((lane^32)<<2) precomputed
__device__ __forceinline__ float wsum64(float x, int a32) {
  x += swzf<0x041F>(x);   // xor 1
  x += swzf<0x081F>(x);   // xor 2
  x += swzf<0x101F>(x);   // xor 4
  x += swzf<0x201F>(x);   // xor 8
  x += swzf<0x401F>(x);   // xor 16
  x += bpermf(a32, x);    // xor 32
  return x;
}

// ---- sortable u32 key mapping (strictly monotone) ----
__device__ __forceinline__ unsigned mapkey(float f) {
  unsigned b = __builtin_bit_cast(unsigned, f);
  unsigned asr = (unsigned)(((int)b) >> 31);
  return b ^ (asr | 0x80000000u);
}
__device__ __forceinline__ float unmapkey(unsigned u) {
  unsigned asr = (unsigned)(((int)u) >> 31);
  unsigned m = (~asr) | 0x80000000u;
  return __builtin_bit_cast(float, u ^ m);
}

// ---- u32 sort building blocks (normalized bitonic: ALL CAS keep min at lower index) ----

__device__ __forceinline__ unsigned umn(unsigned a, unsigned b) { return a < b ? a : b; }
__device__ __forceinline__ unsigned umx(unsigned a, unsigned b) { return a > b ? a : b; }
#define CASU(a,b) { unsigned _mn = umn(a,b); b = umx(a,b); a = _mn; }

// guaranteed-codegen cross-lane CAS select: res = ((p<x) != up(lane)) ? p : x
// = 1 VALU cmp (sgpr dest) + 1 SALU xor (const mask) + 1 VALU cndmask
template<unsigned long long UP>
__device__ __forceinline__ unsigned csel(unsigned x, unsigned p) {
  unsigned long long m;
  asm("v_cmp_lt_u32 %0, %1, %2" : "=s"(m) : "v"(p), "v"(x));
  m ^= UP;
  unsigned res;
  asm("v_cndmask_b32 %0, %1, %2, %3" : "=v"(res) : "v"(x), "v"(p), "s"(m));
  return res;
}

// lane masks: bit set where lane & B
#define U1  0xAAAAAAAAAAAAAAAAULL
#define U2  0xCCCCCCCCCCCCCCCCULL
#define U4  0xF0F0F0F0F0F0F0F0ULL
#define U8  0xFF00FF00FF00FF00ULL
#define U16 0xFFFF0000FFFF0000ULL

template<int IMM, bool REV, unsigned long long UP>
__device__ __forceinline__ void ucpass_swz(unsigned x[8], unsigned y[8]) {
  unsigned px[8], py[8];
  #pragma unroll
  for (int r = 0; r < 8; ++r) {
    const int s = REV ? (7 - r) : r;
    px[r] = uswz<IMM>(x[s]);
    py[r] = uswz<IMM>(y[s]);
  }
  #pragma unroll
  for (int r = 0; r < 8; ++r) {
    x[r] = csel<UP>(x[r], px[r]);
    y[r] = csel<UP>(y[r], py[r]);
  }
}

template<int CTRL, bool REV, unsigned long long UP>
__device__ __forceinline__ void ucpass_dpp(unsigned x[8], unsigned y[8]) {
  unsigned px[8], py[8];
  #pragma unroll
  for (int r = 0; r < 8; ++r) {
    const int s = REV ? (7 - r) : r;
    px[r] = udpp<CTRL>(x[s]);
    py[r] = udpp<CTRL>(y[s]);
  }
  #pragma unroll
  for (int r = 0; r < 8; ++r) {
    x[r] = csel<UP>(x[r], px[r]);
    y[r] = csel<UP>(y[r], py[r]);
  }
}

// in-lane passes
__device__ __forceinline__ void uil_rev_k2(unsigned x[8]) { CASU(x[0],x[1]); CASU(x[2],x[3]); CASU(x[4],x[5]); CASU(x[6],x[7]); }
__device__ __forceinline__ void uil_rev_k4(unsigned x[8]) { CASU(x[0],x[3]); CASU(x[1],x[2]); CASU(x[4],x[7]); CASU(x[5],x[6]); }
__device__ __forceinline__ void uil_rev_k8(unsigned x[8]) { CASU(x[0],x[7]); CASU(x[1],x[6]); CASU(x[2],x[5]); CASU(x[3],x[4]); }
__device__ __forceinline__ void uil_x1(unsigned x[8])     { CASU(x[0],x[1]); CASU(x[2],x[3]); CASU(x[4],x[5]); CASU(x[6],x[7]); }
__device__ __forceinline__ void uil_x2(unsigned x[8])     { CASU(x[0],x[2]); CASU(x[1],x[3]); CASU(x[4],x[6]); CASU(x[5],x[7]); }
__device__ __forceinline__ void uil_x4(unsigned x[8])     { CASU(x[0],x[4]); CASU(x[1],x[5]); CASU(x[2],x[6]); CASU(x[3],x[7]); }
__device__ __forceinline__ void uil_421(unsigned x[8], unsigned y[8]) {
  uil_x4(x); uil_x2(x); uil_x1(x);
  uil_x4(y); uil_x2(y); uil_x1(y);
}

// Kernel 1: per-(tensor,year,col) mean + 5 order stats; fused SE partials.
// One block = (year, 16-col tile); wave w handles col w, both tensors.
// Sort only to k=256 (two ascending runs A=slots 0..255, B=slots 256..367),
// then merge-path binary search in LDS for the 5 exact ranks.
__global__ __launch_bounds__(1024, 8) void k_stats(const float* __restrict__ outp,
                                                   const float* __restrict__ targ,
                                                   float* __restrict__ stats,
                                                   float* __restrict__ se_part)
{
  __shared__ __align__(16) float lds[2][TILE * P];
  __shared__ float seW[16][5];
  const int bx = blockIdx.x;              // 6250 = NYEARS * NTILE
  const int year = bx / NTILE;
  const int tile = bx - year * NTILE;
  const int tid = threadIdx.x;
  const int lane = tid & 63;
  const int wid = tid >> 6;
  const int a32 = ((lane ^ 32) << 2);

  // ---- staging: thread -> col c = tid&15, row-quad q = tid>>4 ----
  // iter1: rows 4q..4q+3 (0..255); iter2 (q<28): rows 256+4q..259+4q (256..367, pad >=365)
  const int c = tid & 15;
  const int q1 = tid >> 4;                // 0..63
  const int gcolL = tile * TILE + c;
  float se = 0.f;
  const size_t ybase = (size_t)year * NDAY * NCOL;
  {
    const int r0 = q1 << 2;               // 0..252
    const size_t g0 = ybase + (size_t)r0 * NCOL + gcolL;
    float a0 = outp[g0], a1 = outp[g0 + NCOL], a2 = outp[g0 + 2*NCOL], a3 = outp[g0 + 3*NCOL];
    float b0 = targ[g0], b1 = targ[g0 + NCOL], b2 = targ[g0 + 2*NCOL], b3 = targ[g0 + 3*NCOL];
    *(float4*)&lds[0][c * P + r0] = (float4){a0, a1, a2, a3};
    *(float4*)&lds[1][c * P + r0] = (float4){b0, b1, b2, b3};
    float d;
    d = a0 - b0; se = fmaf(d, d, se);
    d = a1 - b1; se = fmaf(d, d, se);
    d = a2 - b2; se = fmaf(d, d, se);
    d = a3 - b3; se = fmaf(d, d, se);
  }
  if (q1 < 28) {
    const int r0 = 256 + (q1 << 2);       // 256..364
    const size_t g0 = ybase + (size_t)r0 * NCOL + gcolL;
    const float inf = __builtin_inff();
    float a[4], b[4];
    #pragma unroll
    for (int k = 0; k < 4; ++k) {
      bool val = (r0 + k) < NDAY;         // only q1==27 has pads (rows 365..367)
      a[k] = val ? outp[g0 + (size_t)k * NCOL] : inf;
      b[k] = val ? targ[g0 + (size_t)k * NCOL] : inf;
      if (val) { float d = a[k] - b[k]; se = fmaf(d, d, se); }
    }
    *(float4*)&lds[0][c * P + r0] = (float4){a[0], a[1], a[2], a[3]};
    *(float4*)&lds[1][c * P + r0] = (float4){b[0], b[1], b[2], b[3]};
  }

  // SE reduction: over 4 row-quad groups (lanes l, l^16, l^32, l^48 share col c)
  se += swzf<0x401F>(se);
  se += bpermf(a32, se);
  // then 16 cols -> 5 ny bins within the 16-lane group
  const int nyl = (tile * TILE + (lane & 15)) % 5;
  float sv[5];
  #pragma unroll
  for (int v = 0; v < 5; ++v) {
    float t = (nyl == v) ? se : 0.f;
    t += swzf<0x041F>(t);
    t += swzf<0x081F>(t);
    t += swzf<0x101F>(t);
    t += swzf<0x201F>(t);
    sv[v] = t;
  }
  if (lane == 0) {
    #pragma unroll
    for (int v = 0; v < 5; ++v) seW[wid][v] = sv[v];
  }
  __syncthreads();
  if (tid < 5) {
    float s = 0.f;
    #pragma unroll
    for (int w = 0; w < 16; ++w) s += seW[w][tid];
    se_part[bx * 5 + tid] = s;
  }

  // ---- sort phase: wave wid, col=wid, x = output, y = target ----
  float fx[8], fy[8];
  {
    const float* bx0 = &lds[0][wid * P];
    const float* bx1 = &lds[1][wid * P];
    if (lane < 46) {
      float4 a0 = *(const float4*)(bx0 + (lane << 3));
      float4 a1 = *(const float4*)(bx0 + (lane << 3) + 4);
      fx[0]=a0.x; fx[1]=a0.y; fx[2]=a0.z; fx[3]=a0.w; fx[4]=a1.x; fx[5]=a1.y; fx[6]=a1.z; fx[7]=a1.w;
      float4 b0 = *(const float4*)(bx1 + (lane << 3));
      float4 b1 = *(const float4*)(bx1 + (lane << 3) + 4);
      fy[0]=b0.x; fy[1]=b0.y; fy[2]=b0.z; fy[3]=b0.w; fy[4]=b1.x; fy[5]=b1.y; fy[6]=b1.z; fy[7]=b1.w;
    } else {
      #pragma unroll
      for (int r = 0; r < 8; ++r) { fx[r] = __builtin_inff(); fy[r] = __builtin_inff(); }
    }
  }

  // means over the 365 valid elems (pads are +inf, mask them)
  float sx = 0.f, sy = 0.f;
  {
    const int e0 = lane << 3;
    #pragma unroll
    for (int r = 0; r < 8; ++r) {
      bool valid = (e0 + r) < NDAY;
      sx += valid ? fx[r] : 0.f;
      sy += valid ? fy[r] : 0.f;
    }
  }
  sx = wsum64(sx, a32) * (1.f / 365.f);
  sy = wsum64(sy, a32) * (1.f / 365.f);

  // map to sortable u32 keys
  unsigned x[8], y[8];
  #pragma unroll
  for (int r = 0; r < 8; ++r) { x[r] = mapkey(fx[r]); y[r] = mapkey(fy[r]); }

  // ---- normalized bitonic to k=256 (e = lane*8 + r) ----
  uil_rev_k2(x); uil_rev_k2(y);
  uil_rev_k4(x); uil_rev_k4(y); uil_x1(x); uil_x1(y);
  uil_rev_k8(x); uil_rev_k8(y); uil_x2(x); uil_x2(y); uil_x1(x); uil_x1(y);
  // k=16: rev lane^1 (reg-rev)
  ucpass_dpp<0xB1, true, U1>(x, y);
  uil_421(x, y);
  // k=32: rev lane^3; j8 lane^1
  ucpass_dpp<0x1B, true, U2>(x, y);
  ucpass_dpp<0xB1, false, U1>(x, y);
  uil_421(x, y);
  // k=64: rev lane^7 (ROW_HALF_MIRROR); j16 lane^2; j8 lane^1
  ucpass_dpp<0x141, true, U4>(x, y);
  ucpass_dpp<0x4E, false, U2>(x, y);
  ucpass_dpp<0xB1, false, U1>(x, y);
  uil_421(x, y);
  // k=128: rev lane^15 (ROW_MIRROR); j32 lane^4 swz; j16; j8
  ucpass_dpp<0x140, true, U8>(x, y);
  ucpass_swz<0x101F, false, U4>(x, y);
  ucpass_dpp<0x4E, false, U2>(x, y);
  ucpass_dpp<0xB1, false, U1>(x, y);
  uil_421(x, y);
  // k=256: rev lane^31 swz; j64 lane^8 swz; j32 lane^4 swz; j16; j8
  ucpass_swz<0x7C1F, true, U16>(x, y);
  ucpass_swz<0x201F, false, U8>(x, y);
  ucpass_swz<0x101F, false, U4>(x, y);
  ucpass_dpp<0x4E, false, U2>(x, y);
  ucpass_dpp<0xB1, false, U1>(x, y);
  uil_421(x, y);

  // Lanes 0-31: ascending run A (slots 0..255); lanes 32-63: ascending run B (256..367).
  // Write A|B back into this wave's own staging region: slot = lane*8 + r
  if (lane < 46) {
    float* w0 = &lds[0][wid * P + (lane << 3)];
    float* w1 = &lds[1][wid * P + (lane << 3)];
    float4 v0, v1;
    v0.x = __builtin_bit_cast(float, x[0]); v0.y = __builtin_bit_cast(float, x[1]);
    v0.z = __builtin_bit_cast(float, x[2]); v0.w = __builtin_bit_cast(float, x[3]);
    v1.x = __builtin_bit_cast(float, x[4]); v1.y = __builtin_bit_cast(float, x[5]);
    v1.z = __builtin_bit_cast(float, x[6]); v1.w = __builtin_bit_cast(float, x[7]);
    *(float4*)w0 = v0; *(float4*)(w0 + 4) = v1;
    v0.x = __builtin_bit_cast(float, y[0]); v0.y = __builtin_bit_cast(float, y[1]);
    v0.z = __builtin_bit_cast(float, y[2]); v0.w = __builtin_bit_cast(float, y[3]);
    v1.x = __builtin_bit_cast(float, y[4]); v1.y = __builtin_bit_cast(float, y[5]);
    v1.z = __builtin_bit_cast(float, y[6]); v1.w = __builtin_bit_cast(float, y[7]);
    *(float4*)w1 = v0; *(float4*)(w1 + 4) = v1;
  }
  // same-wave LDS produce->consume: prevent compiler reordering (DS pipe in-order per wave)
  __asm__ __volatile__("" ::: "memory");

  // ---- merge-path selection of ranks {364,357,182,109,7} ----
  const int gc = tile * TILE + wid;
  const size_t sb0 = ((size_t)year * NCOL + gc) * STATS_N;
  const size_t sb1 = ((size_t)(NYEARS + year) * NCOL + gc) * STATS_N;
  if (lane < 10) {
    int q = lane, tz = 0;
    if (lane >= 5) { q = lane - 5; tz = 1; }
    // rank R per q: {364,357,182,109,7}; k1 = R+1
    int k1 = (q == 0) ? 365 : (q == 1) ? 358 : (q == 2) ? 183 : (q == 3) ? 110 : 8;
    const float* base = (tz == 0) ? &lds[0][wid * P] : &lds[1][wid * P];
    // A = base[0..255] (256 keys), B = base[256..364] (109 real keys), both ascending u32
    int lo = k1 - 109; if (lo < 0) lo = 0;
    int hi = (k1 < 256) ? k1 : 256;
    // find max i in [lo,hi] with A[i-1] <= B[k1-i]
    #pragma unroll
    for (int it7 = 0; it7 < 7; ++it7) {
      if (lo < hi) {
        int mid = (lo + hi + 1) >> 1;            // >= 1
        unsigned av = __builtin_bit_cast(unsigned, base[mid - 1]);
        int j = k1 - mid;                         // >= 0
        unsigned bv = (j <= 108) ? __builtin_bit_cast(unsigned, base[256 + j]) : 0xFFFFFFFFu;
        bool ok = av <= bv;
        lo = ok ? mid : lo;
        hi = ok ? hi : mid - 1;
      }
    }
    unsigned aL = (lo >= 1) ? __builtin_bit_cast(unsigned, base[lo - 1]) : 0u;
    int jm = k1 - lo - 1;
    unsigned bL = (jm >= 0) ? __builtin_bit_cast(unsigned, base[256 + jm]) : 0u;
    unsigned ansu = aL > bL ? aL : bL;
    float ans = unmapkey(ansu);
    stats[(tz == 0 ? sb0 : sb1) + 1 + q] = ans;
  } else if (lane == 10) {
    stats[sb0 + 0] = sx;
  } else if (lane == 11) {
    stats[sb1 + 0] = sy;
  }
}

// Kernel 2: Theil-Sen median of 45 pairwise slopes over 10 years, per (col,stat).
__global__ __launch_bounds__(256) void k_trend(const float* __restrict__ stats,
                                               float* __restrict__ trend_part)
{
  const int tid = blockIdx.x * 256 + threadIdx.x;
  const int a32 = (((threadIdx.x & 63) ^ 32) << 2);
  float contrib = 0.f;
  if (tid < K2_THREADS) {
    float med[2];
    #pragma unroll 1
    for (int tz = 0; tz < 2; ++tz) {
      float xv[10];
      #pragma unroll
      for (int y = 0; y < NYEARS; ++y)
        xv[y] = stats[(size_t)tz * (NYEARS * NCOL * STATS_N) + (size_t)y * (NCOL * STATS_N) + tid];
      float d[45];
      int c = 0;
      #pragma unroll
      for (int i = 0; i < 10; ++i) {
        #pragma unroll
        for (int j = i + 1; j < 10; ++j) {
          d[c] = (xv[j] - xv[i]) / (float)(j - i);
          ++c;
        }
      }
      // stable rank-count selection of sorted[22] (lower-middle of 45)
      float m = 0.f;
      #pragma unroll
      for (int i = 0; i < 45; ++i) {
        int rank = 0;
        #pragma unroll
        for (int j = 0; j < 45; ++j) {
          if (j != i) {
            bool lt = (d[j] < d[i]) || ((d[j] == d[i]) && (j < i));
            rank += lt ? 1 : 0;
          }
        }
        m = (rank == 22) ? d[i] : m;
      }
      med[tz] = m;
    }
    float dd = med[1] - med[0];
    contrib = dd * dd;
  }
  float s = wsum64(contrib, a32);
  __shared__ float red[4];
  if ((threadIdx.x & 63) == 0) red[threadIdx.x >> 6] = s;
  __syncthreads();
  if (threadIdx.x == 0) trend_part[blockIdx.x] = red[0] + red[1] + red[2] + red[3];
}

// Kernel 3: deterministic final combine (single block, 1024 threads).
__global__ __launch_bounds__(1024) void k_final(const float* __restrict__ se_part,
                                                const float* __restrict__ trend_part,
                                                float* __restrict__ out)
{
  const int tid = threadIdx.x;
  const int lane = tid & 63;
  const int wid = tid >> 6;
  const int a32 = ((lane ^ 32) << 2);
  float acc[5] = {0.f, 0.f, 0.f, 0.f, 0.f};
  for (int i = tid; i < SE_BLOCKS; i += 1024) {
    #pragma unroll
    for (int v = 0; v < 5; ++v) acc[v] += se_part[i * 5 + v];
  }
  float tr = 0.f;
  for (int i = tid; i < K2_BLOCKS; i += 1024) tr += trend_part[i];

  __shared__ float red[6][16];
  #pragma unroll
  for (int q = 0; q < 6; ++q) {
    float s = wsum64(q < 5 ? acc[q] : tr, a32);
    if (lane == 0) red[q][wid] = s;
  }
  __syncthreads();
  if (tid == 0) {
    float loss = 0.f;
    const float inv = 1.f / (float)((double)NT * (double)NG);
    #pragma unroll
    for (int q = 0; q < 5; ++q) {
      float s = 0.f;
      #pragma unroll
      for (int w = 0; w < 16; ++w) s += red[q][w];
      loss += sqrtf(s * inv);
    }
    float s5 = 0.f;
    #pragma unroll
    for (int w = 0; w < 16; ++w) s5 += red[5][w];
    loss += s5 / (float)NG;
    out[0] = loss;
  }
}

extern "C" void kernel_launch(void* const* d_in, const int* in_sizes, int n_in,
                              void* d_out, int out_size, void* d_ws, size_t ws_size,
                              hipStream_t stream)
{
  const float* outp = (const float*)d_in[0];  // "output" [3650,2000,5] f32
  const float* targ = (const float*)d_in[1];  // "target" [3650,2000,5] f32
  float* out = (float*)d_out;                 // scalar f32 loss

  // ws layout (floats): stats[2*10*10000*6] | se_part[6250*5] | trend_part[235]
  float* stats = (float*)d_ws;
  float* se_part = stats + STATS_FLOATS;
  float* trend_part = se_part + SE_BLOCKS * 5;

  k_stats<<<SE_BLOCKS, 1024, 0, stream>>>(outp, targ, stats, se_part);
  k_trend<<<K2_BLOCKS, 256, 0, stream>>>(stats, trend_part);
  k_final<<<1, 1024, 0, stream>>>(se_part, trend_part, out);
}

// Round 6
// 180.741 us; speedup vs baseline: 1.5875x; 1.5875x over previous
//
#include <hip/hip_runtime.h>
#include <math.h>

// Problem constants
#define NT 3650
#define NG 2000
#define NCOL 10000      // NG*5 flattened (g*5+v)
#define NYEARS 10
#define NDAY 365
#define TILE 16
#define NTILE 625       // NCOL/TILE
#define P 372           // padded LDS col stride in floats (rows 0..367 used)
#define STATS_N 6
#define STATS_FLOATS (2*NYEARS*NCOL*STATS_N)   // 1,200,000 floats
#define SE_BLOCKS (NYEARS*NTILE)               // 6250
#define K2_THREADS (NCOL*STATS_N)              // 60000
#define K2_BLOCKS ((K2_THREADS+255)/256)       // 235

// ---- cross-lane primitives ----
template<int IMM>
__device__ __forceinline__ float swzf(float v) {
  return __builtin_bit_cast(float, __builtin_amdgcn_ds_swizzle(__builtin_bit_cast(int, v), IMM));
}
template<int IMM>
__device__ __forceinline__ unsigned uswz(unsigned v) {
  return (unsigned)__builtin_amdgcn_ds_swizzle((int)v, IMM);
}
__device__ __forceinline__ float bpermf(int addr, float v) {
  return __builtin_bit_cast(float, __builtin_amdgcn_ds_bpermute(addr, __builtin_bit_cast(int, v)));
}
template<int CTRL>
__device__ __forceinline__ unsigned udpp(unsigned v) {
  return (unsigned)__builtin_amdgcn_update_dpp((int)v, (int)v, CTRL, 0xF, 0xF, true);
}

// full-wave float sum (all lanes); a32 = ((lane^32)<<2)
__device__ __forceinline__ float wsum64(float x, int a32) {
  x += swzf<0x041F>(x);
  x += swzf<0x081F>(x);
  x += swzf<0x101F>(x);
  x += swzf<0x201F>(x);
  x += swzf<0x401F>(x);
  x += bpermf(a32, x);
  return x;
}
// 32-lane-half float sum (result in all lanes of each half)
__device__ __forceinline__ float wsum32(float x) {
  x += swzf<0x041F>(x);
  x += swzf<0x081F>(x);
  x += swzf<0x101F>(x);
  x += swzf<0x201F>(x);
  x += swzf<0x401F>(x);
  return x;
}

// ---- sortable u32 key mapping (strictly monotone) ----
__device__ __forceinline__ unsigned mapkey(float f) {
  unsigned b = __builtin_bit_cast(unsigned, f);
  unsigned asr = (unsigned)(((int)b) >> 31);
  return b ^ (asr | 0x80000000u);
}
__device__ __forceinline__ float unmapkey(unsigned u) {
  unsigned asr = (unsigned)(((int)u) >> 31);
  unsigned m = (~asr) | 0x80000000u;
  return __builtin_bit_cast(float, u ^ m);
}

// ---- u32 sort primitives (normalized bitonic: ALL CAS keep min at lower index) ----
__device__ __forceinline__ unsigned umn(unsigned a, unsigned b) { return a < b ? a : b; }
__device__ __forceinline__ unsigned umx(unsigned a, unsigned b) { return a > b ? a : b; }
#define CASU(a,b) { unsigned _mn = umn(a,b); b = umx(a,b); a = _mn; }

// 8-reg cross passes (single array)
template<int IMM, bool REV>
__device__ __forceinline__ void cp8_swz(unsigned a[8], bool up) {
  unsigned p[8];
  #pragma unroll
  for (int r = 0; r < 8; ++r) p[r] = uswz<IMM>(a[REV ? 7 - r : r]);
  #pragma unroll
  for (int r = 0; r < 8; ++r) a[r] = ((p[r] < a[r]) != up) ? p[r] : a[r];
}
template<int CTRL, bool REV>
__device__ __forceinline__ void cp8_dpp(unsigned a[8], bool up) {
  unsigned p[8];
  #pragma unroll
  for (int r = 0; r < 8; ++r) p[r] = udpp<CTRL>(a[REV ? 7 - r : r]);
  #pragma unroll
  for (int r = 0; r < 8; ++r) a[r] = ((p[r] < a[r]) != up) ? p[r] : a[r];
}
// 4-reg cross passes
template<int IMM, bool REV>
__device__ __forceinline__ void cp4_swz(unsigned b[4], bool up) {
  unsigned p[4];
  #pragma unroll
  for (int r = 0; r < 4; ++r) p[r] = uswz<IMM>(b[REV ? 3 - r : r]);
  #pragma unroll
  for (int r = 0; r < 4; ++r) b[r] = ((p[r] < b[r]) != up) ? p[r] : b[r];
}
template<int CTRL, bool REV>
__device__ __forceinline__ void cp4_dpp(unsigned b[4], bool up) {
  unsigned p[4];
  #pragma unroll
  for (int r = 0; r < 4; ++r) p[r] = udpp<CTRL>(b[REV ? 3 - r : r]);
  #pragma unroll
  for (int r = 0; r < 4; ++r) b[r] = ((p[r] < b[r]) != up) ? p[r] : b[r];
}

// in-lane passes, 8 regs
__device__ __forceinline__ void a_rev_k2(unsigned a[8]) { CASU(a[0],a[1]); CASU(a[2],a[3]); CASU(a[4],a[5]); CASU(a[6],a[7]); }
__device__ __forceinline__ void a_rev_k4(unsigned a[8]) { CASU(a[0],a[3]); CASU(a[1],a[2]); CASU(a[4],a[7]); CASU(a[5],a[6]); }
__device__ __forceinline__ void a_rev_k8(unsigned a[8]) { CASU(a[0],a[7]); CASU(a[1],a[6]); CASU(a[2],a[5]); CASU(a[3],a[4]); }
__device__ __forceinline__ void a_x1(unsigned a[8])     { CASU(a[0],a[1]); CASU(a[2],a[3]); CASU(a[4],a[5]); CASU(a[6],a[7]); }
__device__ __forceinline__ void a_x2(unsigned a[8])     { CASU(a[0],a[2]); CASU(a[1],a[3]); CASU(a[4],a[6]); CASU(a[5],a[7]); }
__device__ __forceinline__ void a_x4(unsigned a[8])     { CASU(a[0],a[4]); CASU(a[1],a[5]); CASU(a[2],a[6]); CASU(a[3],a[7]); }
__device__ __forceinline__ void a_421(unsigned a[8])    { a_x4(a); a_x2(a); a_x1(a); }
// in-lane passes, 4 regs
__device__ __forceinline__ void b_rev_k4(unsigned b[4]) { CASU(b[0],b[3]); CASU(b[1],b[2]); }
__device__ __forceinline__ void b_x1(unsigned b[4])     { CASU(b[0],b[1]); CASU(b[2],b[3]); }
__device__ __forceinline__ void b_x2(unsigned b[4])     { CASU(b[0],b[2]); CASU(b[1],b[3]); }

// Kernel 1: per-(tensor,year,col) mean + 5 order stats; fused SE partials.
// One block = (year, 16-col tile). Wave w = col w; lanes 0-31 sort output (X),
// lanes 32-63 sort target (Y), simultaneously: A-run 256 (8 regs) + B-run 128 (4 regs).
// Then merge-path binary search over A(256)+B(109) in LDS for the 5 exact ranks.
__global__ __launch_bounds__(1024, 8) void k_stats(const float* __restrict__ outp,
                                                   const float* __restrict__ targ,
                                                   float* __restrict__ stats,
                                                   float* __restrict__ se_part)
{
  __shared__ __align__(16) float lds[2][TILE * P];
  __shared__ float seW[16][5];
  const int bx = blockIdx.x;              // 6250 = NYEARS * NTILE
  const int year = bx / NTILE;
  const int tile = bx - year * NTILE;
  const int tid = threadIdx.x;
  const int lane = tid & 63;
  const int wid = tid >> 6;
  const int a32 = ((lane ^ 32) << 2);

  // ---- staging: thread -> col c = tid&15, row-quad q = tid>>4 ----
  const int c = tid & 15;
  const int q1 = tid >> 4;                // 0..63
  const int gcolL = tile * TILE + c;
  float se = 0.f;
  const size_t ybase = (size_t)year * NDAY * NCOL;
  {
    const int r0 = q1 << 2;               // 0..252
    const size_t g0 = ybase + (size_t)r0 * NCOL + gcolL;
    float a0 = outp[g0], a1 = outp[g0 + NCOL], a2 = outp[g0 + 2*NCOL], a3 = outp[g0 + 3*NCOL];
    float b0 = targ[g0], b1 = targ[g0 + NCOL], b2 = targ[g0 + 2*NCOL], b3 = targ[g0 + 3*NCOL];
    *(float4*)&lds[0][c * P + r0] = (float4){a0, a1, a2, a3};
    *(float4*)&lds[1][c * P + r0] = (float4){b0, b1, b2, b3};
    float d;
    d = a0 - b0; se = fmaf(d, d, se);
    d = a1 - b1; se = fmaf(d, d, se);
    d = a2 - b2; se = fmaf(d, d, se);
    d = a3 - b3; se = fmaf(d, d, se);
  }
  if (q1 < 28) {
    const int r0 = 256 + (q1 << 2);       // 256..364 (q1==27 covers 364..367 w/ pads)
    const size_t g0 = ybase + (size_t)r0 * NCOL + gcolL;
    const float inf = __builtin_inff();
    float a[4], b[4];
    #pragma unroll
    for (int k = 0; k < 4; ++k) {
      bool val = (r0 + k) < NDAY;
      a[k] = val ? outp[g0 + (size_t)k * NCOL] : inf;
      b[k] = val ? targ[g0 + (size_t)k * NCOL] : inf;
      if (val) { float d = a[k] - b[k]; se = fmaf(d, d, se); }
    }
    *(float4*)&lds[0][c * P + r0] = (float4){a[0], a[1], a[2], a[3]};
    *(float4*)&lds[1][c * P + r0] = (float4){b[0], b[1], b[2], b[3]};
  }

  // SE reduction: lanes l, l^16, l^32, l^48 share col c
  se += swzf<0x401F>(se);
  se += bpermf(a32, se);
  const int nyl = (tile * TILE + (lane & 15)) % 5;
  float sv[5];
  #pragma unroll
  for (int v = 0; v < 5; ++v) {
    float t = (nyl == v) ? se : 0.f;
    t += swzf<0x041F>(t);
    t += swzf<0x081F>(t);
    t += swzf<0x101F>(t);
    t += swzf<0x201F>(t);
    sv[v] = t;
  }
  if (lane == 0) {
    #pragma unroll
    for (int v = 0; v < 5; ++v) seW[wid][v] = sv[v];
  }
  __syncthreads();
  if (tid < 5) {
    float s = 0.f;
    #pragma unroll
    for (int w = 0; w < 16; ++w) s += seW[w][tid];
    se_part[bx * 5 + tid] = s;
  }

  // ---- sort phase: wave wid = col wid; half h: 0 -> output, 1 -> target ----
  const int h = lane >> 5;
  const int l5 = lane & 31;
  const float* base = &lds[h][wid * P];

  float fa[8], fb[4];
  {
    float4 v0 = *(const float4*)(base + (l5 << 3));
    float4 v1 = *(const float4*)(base + (l5 << 3) + 4);
    fa[0]=v0.x; fa[1]=v0.y; fa[2]=v0.z; fa[3]=v0.w; fa[4]=v1.x; fa[5]=v1.y; fa[6]=v1.z; fa[7]=v1.w;
    if (l5 < 28) {
      float4 v2 = *(const float4*)(base + 256 + (l5 << 2));
      fb[0]=v2.x; fb[1]=v2.y; fb[2]=v2.z; fb[3]=v2.w;   // slots 365..367 already +inf from staging
    } else {
      const float inf = __builtin_inff();
      fb[0]=inf; fb[1]=inf; fb[2]=inf; fb[3]=inf;
    }
  }

  // per-tensor mean over 365 valid elems (half-wave sum)
  float sm = 0.f;
  #pragma unroll
  for (int r = 0; r < 8; ++r) sm += fa[r];        // slots 0..255 all valid
  {
    const int e0 = 256 + (l5 << 2);
    #pragma unroll
    for (int r = 0; r < 4; ++r) sm += ((e0 + r) < NDAY) ? fb[r] : 0.f;
  }
  sm = wsum32(sm) * (1.f / 365.f);

  // map to sortable u32 keys
  unsigned A[8], B[4];
  #pragma unroll
  for (int r = 0; r < 8; ++r) A[r] = mapkey(fa[r]);
  #pragma unroll
  for (int r = 0; r < 4; ++r) B[r] = mapkey(fb[r]);

  const bool u1  = (l5 & 1)  != 0;
  const bool u2  = (l5 & 2)  != 0;
  const bool u4  = (l5 & 4)  != 0;
  const bool u8  = (l5 & 8)  != 0;
  const bool u16 = (l5 & 16) != 0;

  // ---- A-net: 256-elem normalized bitonic, e = l5*8 + r ----
  a_rev_k2(A);
  a_rev_k4(A); a_x1(A);
  a_rev_k8(A); a_x2(A); a_x1(A);
  cp8_dpp<0xB1, true>(A, u1);  a_421(A);                                  // k=16
  cp8_dpp<0x1B, true>(A, u2);  cp8_dpp<0xB1, false>(A, u1); a_421(A);     // k=32
  cp8_dpp<0x141, true>(A, u4); cp8_dpp<0x4E, false>(A, u2);
  cp8_dpp<0xB1, false>(A, u1); a_421(A);                                  // k=64
  cp8_dpp<0x140, true>(A, u8); cp8_swz<0x101F, false>(A, u4);
  cp8_dpp<0x4E, false>(A, u2); cp8_dpp<0xB1, false>(A, u1); a_421(A);     // k=128
  cp8_swz<0x7C1F, true>(A, u16); cp8_swz<0x201F, false>(A, u8);
  cp8_swz<0x101F, false>(A, u4); cp8_dpp<0x4E, false>(A, u2);
  cp8_dpp<0xB1, false>(A, u1); a_421(A);                                  // k=256

  // ---- B-net: 128-elem normalized bitonic, e = l5*4 + r ----
  b_x1(B);                                                                // k=2
  b_rev_k4(B); b_x1(B);                                                   // k=4
  cp4_dpp<0xB1, true>(B, u1);  b_x2(B); b_x1(B);                          // k=8
  cp4_dpp<0x1B, true>(B, u2);  cp4_dpp<0xB1, false>(B, u1); b_x2(B); b_x1(B);   // k=16
  cp4_dpp<0x141, true>(B, u4); cp4_dpp<0x4E, false>(B, u2);
  cp4_dpp<0xB1, false>(B, u1); b_x2(B); b_x1(B);                          // k=32
  cp4_dpp<0x140, true>(B, u8); cp4_swz<0x101F, false>(B, u4);
  cp4_dpp<0x4E, false>(B, u2); cp4_dpp<0xB1, false>(B, u1); b_x2(B); b_x1(B);   // k=64
  cp4_swz<0x7C1F, true>(B, u16); cp4_swz<0x201F, false>(B, u8);
  cp4_swz<0x101F, false>(B, u4); cp4_dpp<0x4E, false>(B, u2);
  cp4_dpp<0xB1, false>(B, u1); b_x2(B); b_x1(B);                          // k=128

  // write back sorted runs: A -> slots 0..255, B -> slots 256..367 (l5<28)
  {
    float* w = &lds[h][wid * P + (l5 << 3)];
    float4 v0, v1;
    v0.x = __builtin_bit_cast(float, A[0]); v0.y = __builtin_bit_cast(float, A[1]);
    v0.z = __builtin_bit_cast(float, A[2]); v0.w = __builtin_bit_cast(float, A[3]);
    v1.x = __builtin_bit_cast(float, A[4]); v1.y = __builtin_bit_cast(float, A[5]);
    v1.z = __builtin_bit_cast(float, A[6]); v1.w = __builtin_bit_cast(float, A[7]);
    *(float4*)w = v0; *(float4*)(w + 4) = v1;
    if (l5 < 28) {
      float4 v2;
      v2.x = __builtin_bit_cast(float, B[0]); v2.y = __builtin_bit_cast(float, B[1]);
      v2.z = __builtin_bit_cast(float, B[2]); v2.w = __builtin_bit_cast(float, B[3]);
      *(float4*)&lds[h][wid * P + 256 + (l5 << 2)] = v2;
    }
  }
  __asm__ __volatile__("" ::: "memory");   // same-wave LDS produce->consume ordering

  // ---- merge-path selection of ranks {364,357,182,109,7} ----
  const int gc = tile * TILE + wid;
  const size_t sb0 = ((size_t)year * NCOL + gc) * STATS_N;
  const size_t sb1 = ((size_t)(NYEARS + year) * NCOL + gc) * STATS_N;
  if (lane < 10) {
    int q = lane, tz = 0;
    if (lane >= 5) { q = lane - 5; tz = 1; }
    int k1 = (q == 0) ? 365 : (q == 1) ? 358 : (q == 2) ? 183 : (q == 3) ? 110 : 8;
    const float* mb = (tz == 0) ? &lds[0][wid * P] : &lds[1][wid * P];
    int lo = k1 - 109; if (lo < 0) lo = 0;
    int hi = (k1 < 256) ? k1 : 256;
    #pragma unroll
    for (int it7 = 0; it7 < 7; ++it7) {
      if (lo < hi) {
        int mid = (lo + hi + 1) >> 1;
        unsigned av = __builtin_bit_cast(unsigned, mb[mid - 1]);
        int j = k1 - mid;
        unsigned bv = (j <= 108) ? __builtin_bit_cast(unsigned, mb[256 + j]) : 0xFFFFFFFFu;
        bool ok = av <= bv;
        lo = ok ? mid : lo;
        hi = ok ? hi : mid - 1;
      }
    }
    unsigned aL = (lo >= 1) ? __builtin_bit_cast(unsigned, mb[lo - 1]) : 0u;
    int jm = k1 - lo - 1;
    unsigned bL = (jm >= 0) ? __builtin_bit_cast(unsigned, mb[256 + jm]) : 0u;
    unsigned ansu = aL > bL ? aL : bL;
    stats[(tz == 0 ? sb0 : sb1) + 1 + q] = unmapkey(ansu);
  }
  if (lane == 0)  stats[sb0 + 0] = sm;
  if (lane == 32) stats[sb1 + 0] = sm;
}

// Kernel 2: Theil-Sen median of 45 pairwise slopes over 10 years, per (col,stat).
// Slopes sorted by a Batcher odd-even-merge network on 64 (45 + 19 inf pads); median = d[22].
#define CASF(a,b) { float _mn = fminf(a,b); b = fmaxf(a,b); a = _mn; }
__global__ __launch_bounds__(256) void k_trend(const float* __restrict__ stats,
                                               float* __restrict__ trend_part)
{
  const int tid = blockIdx.x * 256 + threadIdx.x;
  const int a32 = (((threadIdx.x & 63) ^ 32) << 2);
  float contrib = 0.f;
  if (tid < K2_THREADS) {
    const float rc[10] = {0.f, 1.f, 0.5f, 1.f/3.f, 0.25f, 0.2f, 1.f/6.f, 1.f/7.f, 0.125f, 1.f/9.f};
    float med[2];
    #pragma unroll 1
    for (int tz = 0; tz < 2; ++tz) {
      float xv[10];
      #pragma unroll
      for (int y = 0; y < NYEARS; ++y)
        xv[y] = stats[(size_t)tz * (NYEARS * NCOL * STATS_N) + (size_t)y * (NCOL * STATS_N) + tid];
      float d[64];
      int cI = 0;
      #pragma unroll
      for (int i = 0; i < 10; ++i) {
        #pragma unroll
        for (int j = i + 1; j < 10; ++j) {
          d[cI] = (xv[j] - xv[i]) * rc[j - i];
          ++cI;
        }
      }
      #pragma unroll
      for (int i = 45; i < 64; ++i) d[i] = __builtin_inff();
      // Batcher odd-even mergesort, n=64 (all indices compile-time)
      #pragma unroll
      for (int p = 1; p < 64; p <<= 1) {
        #pragma unroll
        for (int k = p; k > 0; k >>= 1) {
          #pragma unroll
          for (int j = k & (p - 1); j + k < 64; j += 2 * k) {
            #pragma unroll
            for (int i = 0; i < k; ++i) {
              if ((i + j) / (2 * p) == (i + j + k) / (2 * p)) {
                CASF(d[i + j], d[i + j + k]);
              }
            }
          }
        }
      }
      med[tz] = d[22];
    }
    float dd = med[1] - med[0];
    contrib = dd * dd;
  }
  float s = wsum64(contrib, a32);
  __shared__ float red[4];
  if ((threadIdx.x & 63) == 0) red[threadIdx.x >> 6] = s;
  __syncthreads();
  if (threadIdx.x == 0) trend_part[blockIdx.x] = red[0] + red[1] + red[2] + red[3];
}

// Kernel 3: deterministic final combine (single block, 1024 threads).
__global__ __launch_bounds__(1024) void k_final(const float* __restrict__ se_part,
                                                const float* __restrict__ trend_part,
                                                float* __restrict__ out)
{
  const int tid = threadIdx.x;
  const int lane = tid & 63;
  const int wid = tid >> 6;
  const int a32 = ((lane ^ 32) << 2);
  float acc[5] = {0.f, 0.f, 0.f, 0.f, 0.f};
  for (int i = tid; i < SE_BLOCKS; i += 1024) {
    #pragma unroll
    for (int v = 0; v < 5; ++v) acc[v] += se_part[i * 5 + v];
  }
  float tr = 0.f;
  for (int i = tid; i < K2_BLOCKS; i += 1024) tr += trend_part[i];

  __shared__ float red[6][16];
  #pragma unroll
  for (int q = 0; q < 6; ++q) {
    float s = wsum64(q < 5 ? acc[q] : tr, a32);
    if (lane == 0) red[q][wid] = s;
  }
  __syncthreads();
  if (tid == 0) {
    float loss = 0.f;
    const float inv = 1.f / (float)((double)NT * (double)NG);
    #pragma unroll
    for (int q = 0; q < 5; ++q) {
      float s = 0.f;
      #pragma unroll
      for (int w = 0; w < 16; ++w) s += red[q][w];
      loss += sqrtf(s * inv);
    }
    float s5 = 0.f;
    #pragma unroll
    for (int w = 0; w < 16; ++w) s5 += red[5][w];
    loss += s5 / (float)NG;
    out[0] = loss;
  }
}

extern "C" void kernel_launch(void* const* d_in, const int* in_sizes, int n_in,
                              void* d_out, int out_size, void* d_ws, size_t ws_size,
                              hipStream_t stream)
{
  const float* outp = (const float*)d_in[0];  // "output" [3650,2000,5] f32
  const float* targ = (const float*)d_in[1];  // "target" [3650,2000,5] f32
  float* out = (float*)d_out;                 // scalar f32 loss

  // ws layout (floats): stats[2*10*10000*6] | se_part[6250*5] | trend_part[235]
  float* stats = (float*)d_ws;
  float* se_part = stats + STATS_FLOATS;
  float* trend_part = se_part + SE_BLOCKS * 5;

  k_stats<<<SE_BLOCKS, 1024, 0, stream>>>(outp, targ, stats, se_part);
  k_trend<<<K2_BLOCKS, 256, 0, stream>>>(stats, trend_part);
  k_final<<<1, 1024, 0, stream>>>(se_part, trend_part, out);
}